// Round 3
// baseline (1522.308 us; speedup 1.0000x reference)
//
#include <hip/hip_runtime.h>

typedef _Float16 half_t;
typedef _Float16 half8 __attribute__((ext_vector_type(8)));
typedef _Float16 half4v __attribute__((ext_vector_type(4)));
typedef float floatx4 __attribute__((ext_vector_type(4)));

#define MFMA(a,b,c) __builtin_amdgcn_mfma_f32_16x16x32_f16(a,b,c,0,0,0)

#define NB 16
#define NLEN 1024
#define DD 128
#define BN (NB*NLEN)
#define BND ((size_t)NB*NLEN*DD)
#define BNN ((size_t)NB*NLEN*NLEN)

// ---------------------------------------------------------------- embed: h = x @ Ew^T (fp32, once)
__global__ __launch_bounds__(256)
void k_embed(const float* __restrict__ x, const float* __restrict__ Ew, float* __restrict__ h) {
    __shared__ float rows[8][DD];
    int g = blockIdx.x * 8;
    int tid = threadIdx.x;
    {
        int nl = tid >> 5, c4 = (tid & 31) * 4;
        *(float4*)&rows[nl][c4] = *(const float4*)&x[(size_t)(g + nl) * DD + c4];
    }
    __syncthreads();
    int t = tid & 127, half = tid >> 7;
    const float* wr = Ew + (size_t)t * DD;
    float acc[4] = {0.f, 0.f, 0.f, 0.f};
    for (int k = 0; k < DD; k++) {
        float w = wr[k];
#pragma unroll
        for (int m = 0; m < 4; m++) acc[m] += rows[half + 2 * m][k] * w;
    }
#pragma unroll
    for (int m = 0; m < 4; m++) h[(size_t)(g + half + 2 * m) * DD + t] = acc[m];
}

// ---------------- adjacency -> bitmask
__global__ __launch_bounds__(256)
void k_adjmask(const float* __restrict__ adj, unsigned int* __restrict__ mask) {
    int widx = blockIdx.x * 256 + threadIdx.x;
    const float* p = adj + (size_t)widx * 32;
    unsigned int m = 0;
#pragma unroll
    for (int i = 0; i < 32; i += 4) {
        float4 v = *(const float4*)&p[i];
        m |= (v.x > 0.f ? 1u : 0u) << i;
        m |= (v.y > 0.f ? 1u : 0u) << (i + 1);
        m |= (v.z > 0.f ? 1u : 0u) << (i + 2);
        m |= (v.w > 0.f ? 1u : 0u) << (i + 3);
    }
    mask[widx] = m;
}

// ---------------- weight casts: Wf16 = gW row-major; ATf16[e][d] = gA[d][e]
__global__ __launch_bounds__(256)
void k_wcast(const float* __restrict__ gW, const float* __restrict__ gA,
             half_t* __restrict__ Wf, half_t* __restrict__ ATf) {
    int i = blockIdx.x * 256 + threadIdx.x;
    Wf[i] = (half_t)gW[i];
    int lrem = i & 16383;
    int d = lrem >> 7, e = lrem & 127;
    ATf[(i & ~16383) + (e << 7) + d] = (half_t)gA[i];
}

// ---------------- proj (MFMA): in = pa - pb (pb nullable); hbr = in@W^T+b ; hA = hbr@A
// outputs: hbr f32, hbr16, hA16 row-major, zT0 = hbr^T f16; also zeroes rsb
__global__ __launch_bounds__(256)
void k_proj(const float* __restrict__ pa, const float* __restrict__ pb,
            const half_t* __restrict__ Wf, const float* __restrict__ bias,
            const half_t* __restrict__ ATf,
            float* __restrict__ hbr, half_t* __restrict__ hbr16, half_t* __restrict__ hA16,
            half_t* __restrict__ zT0, float* __restrict__ rsbz) {
    __shared__ half_t htile[32 * 136];
    __shared__ half_t hbtile[32 * 136];
    int gblk = blockIdx.x;
    int g = gblk * 32;
    int t = threadIdx.x;
    if (gblk < 64) rsbz[gblk * 256 + t] = 0.f;
    int w = t >> 6, l = t & 63, q = l >> 4, l15 = l & 15;
#pragma unroll
    for (int v = 0; v < 4; v++) {
        int idx = v * 256 + t; int r = idx >> 5, c4 = (idx & 31) * 4;
        size_t gi = ((size_t)(g + r) << 7) + c4;
        float4 hv = *(const float4*)&pa[gi];
        if (pb) {
            float4 bv = *(const float4*)&pb[gi];
            hv.x -= bv.x; hv.y -= bv.y; hv.z -= bv.z; hv.w -= bv.w;
        }
        half4v hh = {(half_t)hv.x, (half_t)hv.y, (half_t)hv.z, (half_t)hv.w};
        *(half4v*)&htile[r * 136 + c4] = hh;
    }
    __syncthreads();
    int rowh = (w & 1) * 16;
    int c0 = (w >> 1) * 4;
    half8 a1[4];
#pragma unroll
    for (int kc = 0; kc < 4; kc++) a1[kc] = *(const half8*)&htile[(rowh + l15) * 136 + kc * 32 + q * 8];
    floatx4 acc[4];
#pragma unroll
    for (int cc = 0; cc < 4; cc++) {
        int col = (c0 + cc) * 16 + l15;
        floatx4 a = {0.f, 0.f, 0.f, 0.f};
#pragma unroll
        for (int kc = 0; kc < 4; kc++) {
            half8 bf = *(const half8*)&Wf[((size_t)col << 7) + kc * 32 + q * 8];
            a = MFMA(a1[kc], bf, a);
        }
        float bv = bias[col];
        a.x += bv; a.y += bv; a.z += bv; a.w += bv;
        acc[cc] = a;
    }
#pragma unroll
    for (int cc = 0; cc < 4; cc++) {
        int col = (c0 + cc) * 16 + l15;
#pragma unroll
        for (int r = 0; r < 4; r++) {
            int rowl = rowh + q * 4 + r;
            float vv = acc[cc][r];
            hbr[((size_t)(g + rowl) << 7) + col] = vv;
            hbtile[rowl * 136 + col] = (half_t)vv;
        }
    }
    __syncthreads();
    // zT0 = hbr^T write: 128 d x 32 n
    {
        int d = t >> 1, ns = (t & 1) * 16;
        half8 t0, t1;
#pragma unroll
        for (int i = 0; i < 8; i++) t0[i] = hbtile[(ns + i) * 136 + d];
#pragma unroll
        for (int i = 0; i < 8; i++) t1[i] = hbtile[(ns + 8 + i) * 136 + d];
        size_t zbase = ((size_t)((g >> 10) * 128 + d) << 10) + (g & 1023) + ns;
        *(half8*)&zT0[zbase] = t0;
        *(half8*)&zT0[zbase + 8] = t1;
    }
    half8 a2[4];
#pragma unroll
    for (int kc = 0; kc < 4; kc++) a2[kc] = *(const half8*)&hbtile[(rowh + l15) * 136 + kc * 32 + q * 8];
#pragma unroll
    for (int cc = 0; cc < 4; cc++) {
        int col = (c0 + cc) * 16 + l15;
        floatx4 a = {0.f, 0.f, 0.f, 0.f};
#pragma unroll
        for (int kc = 0; kc < 4; kc++) {
            half8 bf = *(const half8*)&ATf[((size_t)col << 7) + kc * 32 + q * 8];
            a = MFMA(a2[kc], bf, a);
        }
        acc[cc] = a;
    }
    __syncthreads();
#pragma unroll
    for (int cc = 0; cc < 4; cc++) {
        int col = (c0 + cc) * 16 + l15;
#pragma unroll
        for (int r = 0; r < 4; r++) htile[(rowh + q * 4 + r) * 136 + col] = (half_t)acc[cc][r];
    }
    __syncthreads();
#pragma unroll
    for (int v = 0; v < 2; v++) {
        int idx = v * 256 + t; int r = idx >> 4, c8 = (idx & 15) * 8;
        *(half8*)&hA16[((size_t)(g + r) << 7) + c8] = *(const half8*)&htile[r * 136 + c8];
        *(half8*)&hbr16[((size_t)(g + r) << 7) + c8] = *(const half8*)&hbtile[r * 136 + c8];
    }
}

// ---------------- triangular fused E: tile(ti,tj) ti<=tj of em = hA_i.hbr_j + hbr_i.hA_j (symmetric)
// E2 = edge ? exp(em-8) : 0 (f16), written to both mirror tiles; rsb += row/col sums of exp((edge?em:0)-8)
__global__ __launch_bounds__(256)
void k_E(const half_t* __restrict__ hA16, const half_t* __restrict__ hbr16,
         const unsigned int* __restrict__ maskG, half_t* __restrict__ E2,
         float* __restrict__ rsb) {
    int b = blockIdx.z, ti = blockIdx.y, tj = blockIdx.x;
    if (ti > tj) return;
    __shared__ half_t Ai[64 * 136];
    __shared__ half_t Hi[64 * 136];
    __shared__ half_t est[64 * 72];
    __shared__ unsigned int maskS[128];
    __shared__ float rowp[4][64];
    __shared__ float colp[64];
    int t = threadIdx.x, w = t >> 6, l = t & 63, q = l >> 4, l15 = l & 15;
    const half_t* Ab = hA16 + ((size_t)b << 17);
    const half_t* Hb = hbr16 + ((size_t)b << 17);
#pragma unroll
    for (int v = 0; v < 4; v++) {
        int idx = v * 256 + t; int r = idx >> 4, c8 = (idx & 15) * 8;
        *(half8*)&Ai[r * 136 + c8] = *(const half8*)&Ab[((size_t)(ti * 64 + r) << 7) + c8];
        *(half8*)&Hi[r * 136 + c8] = *(const half8*)&Hb[((size_t)(ti * 64 + r) << 7) + c8];
    }
    if (t < 128) maskS[t] = maskG[(size_t)(b * 1024 + ti * 64 + (t >> 1)) * 32 + tj * 2 + (t & 1)];
    // j-side fragments direct from global (L2-hot)
    half8 FHj[4], FAj[4];
    int jr = tj * 64 + w * 16 + l15;
#pragma unroll
    for (int kc = 0; kc < 4; kc++) {
        FHj[kc] = *(const half8*)&Hb[((size_t)jr << 7) + kc * 32 + q * 8];
        FAj[kc] = *(const half8*)&Ab[((size_t)jr << 7) + kc * 32 + q * 8];
    }
    __syncthreads();
    floatx4 acc[4];
#pragma unroll
    for (int rt = 0; rt < 4; rt++) {
        floatx4 a = {0.f, 0.f, 0.f, 0.f};
#pragma unroll
        for (int kc = 0; kc < 4; kc++) {
            a = MFMA(*(const half8*)&Ai[(rt * 16 + l15) * 136 + kc * 32 + q * 8], FHj[kc], a);
            a = MFMA(*(const half8*)&Hi[(rt * 16 + l15) * 136 + kc * 32 + q * 8], FAj[kc], a);
        }
        acc[rt] = a;
    }
    const float CN = 0.000335462627903f;   // exp(-8)
    int jc = w * 16 + l15;
    float colsum = 0.f;
#pragma unroll
    for (int rt = 0; rt < 4; rt++) {
#pragma unroll
        for (int r = 0; r < 4; r++) {
            int row = rt * 16 + q * 4 + r;
            bool edge = (maskS[row * 2 + (jc >> 5)] >> (jc & 31)) & 1u;
            float tv = edge ? __expf(acc[rt][r] - 8.f) : CN;
            est[row * 72 + jc] = edge ? (half_t)tv : (half_t)0.f;
            colsum += tv;
            float rs = tv;
            rs += __shfl_xor(rs, 1); rs += __shfl_xor(rs, 2);
            rs += __shfl_xor(rs, 4); rs += __shfl_xor(rs, 8);
            if (l15 == 0) rowp[w][row] = rs;
        }
    }
    colsum += __shfl_xor(colsum, 16);
    colsum += __shfl_xor(colsum, 32);
    if (q == 0) colp[jc] = colsum;
    __syncthreads();
#pragma unroll
    for (int v = 0; v < 2; v++) {
        int idx = v * 256 + t; int r = idx >> 3, c8 = (idx & 7) * 8;
        *(half8*)&E2[((size_t)b << 20) + ((size_t)(ti * 64 + r) << 10) + tj * 64 + c8]
            = *(const half8*)&est[r * 72 + c8];
    }
    if (ti != tj) {
#pragma unroll
        for (int v = 0; v < 2; v++) {
            int idx = v * 256 + t; int r = idx >> 3, c8 = (idx & 7) * 8;
            half8 tmp;
#pragma unroll
            for (int i = 0; i < 8; i++) tmp[i] = est[(c8 + i) * 72 + r];
            *(half8*)&E2[((size_t)b << 20) + ((size_t)(tj * 64 + r) << 10) + ti * 64 + c8] = tmp;
        }
    }
    if (t < 64) {
        float rsum = rowp[0][t] + rowp[1][t] + rowp[2][t] + rowp[3][t];
        atomicAdd(&rsb[b * 1024 + ti * 64 + t], rsum);
        if (ti != tj) atomicAdd(&rsb[b * 1024 + tj * 64 + t], colp[t]);
    }
}

// ---------------- rsr16 = f16(1/rssum)
__global__ __launch_bounds__(256)
void k_rsinv(const float* __restrict__ rsb, half_t* __restrict__ rsr16) {
    int i = blockIdx.x * 256 + threadIdx.x;
    rsr16[i] = (half_t)(1.f / rsb[i]);
}

// ---------------- az = (E2 .* rs) @ z  (f16 MFMA, rs folded into A-tile)
// mode0: outF = relu(az) row-major. mode1: z=c*h+(1-c)*relu(az), write zT only. mode2: write zf f32 only.
__global__ __launch_bounds__(256)
void k_az(const half_t* __restrict__ E2, const half_t* __restrict__ rsr16,
          const half_t* __restrict__ zTin, const float* __restrict__ hbr,
          const float* __restrict__ cfb, float* __restrict__ outF,
          half_t* __restrict__ zTout, int mode) {
    __shared__ half_t Pt[32 * 72];
    __shared__ half_t Zt[128 * 72];
    int b = blockIdx.y, i0 = blockIdx.x * 32;
    int t = threadIdx.x;
    int w = t >> 6, l = t & 63, q = l >> 4, l15 = l & 15;
    int rowg = (w & 1) * 16, colh = (w >> 1) * 64;
    floatx4 acc[4] = {};
    for (int k0 = 0; k0 < 1024; k0 += 64) {
        {
            int r = t >> 3, c8 = (t & 7) * 8;
            half8 ev = *(const half8*)&E2[((size_t)b << 20) + ((size_t)(i0 + r) << 10) + k0 + c8];
            half8 rv = *(const half8*)&rsr16[b * 1024 + k0 + c8];
            *(half8*)&Pt[r * 72 + c8] = ev * rv;
        }
#pragma unroll
        for (int v = 0; v < 4; v++) {
            int idx = v * 256 + t; int r = idx >> 3, c8 = (idx & 7) * 8;
            *(half8*)&Zt[r * 72 + c8] = *(const half8*)&zTin[((size_t)(b * 128 + r) << 10) + k0 + c8];
        }
        __syncthreads();
        half8 af0 = *(const half8*)&Pt[(rowg + l15) * 72 + q * 8];
        half8 af1 = *(const half8*)&Pt[(rowg + l15) * 72 + 32 + q * 8];
#pragma unroll
        for (int cc = 0; cc < 4; cc++) {
            acc[cc] = MFMA(af0, *(const half8*)&Zt[(colh + cc * 16 + l15) * 72 + q * 8], acc[cc]);
            acc[cc] = MFMA(af1, *(const half8*)&Zt[(colh + cc * 16 + l15) * 72 + 32 + q * 8], acc[cc]);
        }
        __syncthreads();
    }
    int nodeb = i0 + rowg + q * 4;
    if (mode == 0) {
#pragma unroll
        for (int cc = 0; cc < 4; cc++) {
            int col = colh + cc * 16 + l15;
#pragma unroll
            for (int r = 0; r < 4; r++)
                outF[((size_t)(b * 1024 + nodeb + r) << 7) + col] = fmaxf(acc[cc][r], 0.f);
        }
    } else {
        float4 cf4 = *(const float4*)&cfb[b * 1024 + nodeb];
        const float* cfp = &cf4.x;
#pragma unroll
        for (int cc = 0; cc < 4; cc++) {
            int col = colh + cc * 16 + l15;
            half4v zt;
#pragma unroll
            for (int r = 0; r < 4; r++) {
                float azv = fmaxf(acc[cc][r], 0.f);
                float hv = hbr[((size_t)(b * 1024 + nodeb + r) << 7) + col];
                float zv = cfp[r] * hv + (1.f - cfp[r]) * azv;
                if (mode == 2) outF[((size_t)(b * 1024 + nodeb + r) << 7) + col] = zv;
                zt[r] = (half_t)zv;
            }
            if (mode == 1) *(half4v*)&zTout[((size_t)(b * 128 + col) << 10) + nodeb] = zt;
        }
    }
}

// ---------------- fused gate: cf = sigmoid([hbr,az].gw+gb); z = cf*hbr+(1-cf)*az;
// gmode0: write zT (f16 z^T); gmode1: write zf (f32, final). Always writes cfb.
__global__ __launch_bounds__(256)
void k_gate(const float* __restrict__ hbr, const float* __restrict__ az,
            const float* __restrict__ gw, const float* __restrict__ gb_,
            float* __restrict__ cfb, float* __restrict__ zf, half_t* __restrict__ zT,
            int gmode) {
    __shared__ float cfs[64];
    __shared__ half_t tile[128 * 72];
    int n0g = blockIdx.x * 64;
    int b = n0g >> 10, nl0 = n0g & 1023;
    int t = threadIdx.x;
    int node = t >> 2, seg = t & 3;
    {
        const float* src = (seg < 2) ? hbr : az;
        const float* row = src + ((size_t)(n0g + node) << 7) + (seg & 1) * 64;
        const float* gwp = gw + seg * 64;
        float acc = 0.f;
#pragma unroll
        for (int i = 0; i < 64; i += 4) {
            float4 v = *(const float4*)&row[i];
            float4 g = *(const float4*)&gwp[i];
            acc += v.x * g.x + v.y * g.y + v.z * g.z + v.w * g.w;
        }
        acc += __shfl_xor(acc, 1);
        acc += __shfl_xor(acc, 2);
        if (seg == 0) {
            float cf = 1.f / (1.f + __expf(-(acc + gb_[0])));
            cfs[node] = cf;
            cfb[n0g + node] = cf;
        }
    }
    __syncthreads();
#pragma unroll
    for (int v = 0; v < 8; v++) {
        int idx = v * 256 + t; int r = idx >> 5, c4 = (idx & 31) * 4;
        size_t gi = ((size_t)(n0g + r) << 7) + c4;
        float4 hv = *(const float4*)&hbr[gi];
        float4 av = *(const float4*)&az[gi];
        float cf = cfs[r];
        float4 zv;
        zv.x = cf * hv.x + (1.f - cf) * av.x;
        zv.y = cf * hv.y + (1.f - cf) * av.y;
        zv.z = cf * hv.z + (1.f - cf) * av.z;
        zv.w = cf * hv.w + (1.f - cf) * av.w;
        if (gmode == 1) *(float4*)&zf[gi] = zv;
        tile[(c4 + 0) * 72 + r] = (half_t)zv.x;
        tile[(c4 + 1) * 72 + r] = (half_t)zv.y;
        tile[(c4 + 2) * 72 + r] = (half_t)zv.z;
        tile[(c4 + 3) * 72 + r] = (half_t)zv.w;
    }
    if (gmode == 0) {
        __syncthreads();
#pragma unroll
        for (int v = 0; v < 4; v++) {
            int idx = v * 256 + t; int d = idx >> 3, c8 = (idx & 7) * 8;
            *(half8*)&zT[((size_t)(b * 128 + d) << 10) + nl0 + c8] = *(const half8*)&tile[d * 72 + c8];
        }
    }
}

// ---------------- partial masked pool of (z2-z1)
__global__ __launch_bounds__(256)
void k_pool(const float* __restrict__ z2, const float* __restrict__ z1,
            const float* __restrict__ valid, float* __restrict__ part) {
    int b = blockIdx.y, s = blockIdx.x;
    int t = threadIdx.x, d = t & 127, hf = t >> 7;
    __shared__ float red[128];
    float acc = 0.f;
    int nbase = s * 128 + hf * 64;
    for (int n = nbase; n < nbase + 64; n++) {
        size_t gi = ((size_t)(b * 1024 + n) << 7) + d;
        acc += (z2[gi] - z1[gi]) * valid[b * 1024 + n];
    }
    if (hf) red[d] = acc;
    __syncthreads();
    if (!hf) part[(b * 8 + s) * 128 + d] = acc + red[d];
}

// ---------------- final reduce + MLP head
__global__ __launch_bounds__(128)
void k_mlp(const float* __restrict__ part, const float* __restrict__ valid,
           const float* __restrict__ w0, const float* __restrict__ b0,
           const float* __restrict__ w1, const float* __restrict__ b1,
           const float* __restrict__ w2, const float* __restrict__ b2,
           const float* __restrict__ w3, const float* __restrict__ b3,
           float* __restrict__ out) {
    int b = blockIdx.x, t = threadIdx.x;
    __shared__ float y0[DD], y1[DD];
    __shared__ float sred[2];
    float vs = 0.f;
    for (int n = t; n < NLEN; n += 128) vs += valid[b * NLEN + n];
    for (int off = 32; off; off >>= 1) vs += __shfl_down(vs, off);
    if ((t & 63) == 0) sred[t >> 6] = vs;
    __syncthreads();
    float vsum = sred[0] + sred[1];
    float acc = 0.f;
#pragma unroll
    for (int s = 0; s < 8; s++) acc += part[(b * 8 + s) * 128 + t];
    y0[t] = acc / vsum;
    __syncthreads();
    float a = b0[t];
    for (int k = 0; k < DD; k++) a += y0[k] * w0[t * DD + k];
    y1[t] = fmaxf(a, 0.f);
    __syncthreads();
    a = b1[t];
    for (int k = 0; k < DD; k++) a += y1[k] * w1[t * DD + k];
    y0[t] = fmaxf(a, 0.f);
    __syncthreads();
    a = b2[t];
    for (int k = 0; k < DD; k++) a += y0[k] * w2[t * DD + k];
    y1[t] = fmaxf(a, 0.f);
    __syncthreads();
    float p = y1[t] * w3[t];
    for (int off = 32; off; off >>= 1) p += __shfl_down(p, off);
    if ((t & 63) == 0) sred[t >> 6] = p;
    __syncthreads();
    if (t == 0) out[b] = 1.f / (1.f + __expf(-(sred[0] + sred[1] + b3[0])));
}

extern "C" void kernel_launch(void* const* d_in, const int* in_sizes, int n_in,
                              void* d_out, int out_size, void* d_ws, size_t ws_size,
                              hipStream_t stream) {
    (void)in_sizes; (void)n_in; (void)out_size; (void)ws_size;
    const float* x     = (const float*)d_in[0];
    const float* adj1  = (const float*)d_in[1];
    const float* adj2  = (const float*)d_in[2];
    const float* valid = (const float*)d_in[3];
    const float* Ew    = (const float*)d_in[4];
    const float* gW    = (const float*)d_in[5];
    const float* gb    = (const float*)d_in[6];
    const float* gA    = (const float*)d_in[7];
    const float* gatew = (const float*)d_in[8];
    const float* gateb = (const float*)d_in[9];
    const float* w0 = (const float*)d_in[10]; const float* b0 = (const float*)d_in[11];
    const float* w1 = (const float*)d_in[12]; const float* b1 = (const float*)d_in[13];
    const float* w2 = (const float*)d_in[14]; const float* b2 = (const float*)d_in[15];
    const float* w3 = (const float*)d_in[16]; const float* b3 = (const float*)d_in[17];
    float* out = (float*)d_out;

    char* p = (char*)d_ws;
    float* h    = (float*)p; p += BND * 4;
    float* hbr  = (float*)p; p += BND * 4;
    float* az   = (float*)p; p += BND * 4;
    float* z1   = (float*)p; p += BND * 4;
    float* z2   = (float*)p; p += BND * 4;
    float* rsb  = (float*)p; p += BN * 4;
    float* cfb  = (float*)p; p += BN * 4;
    float* partb = (float*)p; p += (size_t)NB * 8 * 128 * 4;
    half_t* rsr16 = (half_t*)p; p += BN * 2;
    half_t* hbr16 = (half_t*)p; p += BND * 2;
    half_t* hA16  = (half_t*)p; p += BND * 2;
    half_t* E2    = (half_t*)p; p += BNN * 2;
    half_t* zT0   = (half_t*)p; p += BND * 2;
    half_t* zT1   = (half_t*)p; p += BND * 2;
    unsigned int* mask1 = (unsigned int*)p; p += (BNN / 32) * 4;
    unsigned int* mask2 = (unsigned int*)p; p += (BNN / 32) * 4;
    half_t* Wf16 = (half_t*)p; p += (size_t)4 * 128 * 128 * 2;
    half_t* AT16 = (half_t*)p; p += (size_t)4 * 128 * 128 * 2;

    k_wcast<<<256, 256, 0, stream>>>(gW, gA, Wf16, AT16);
    k_adjmask<<<2048, 256, 0, stream>>>(adj1, mask1);
    k_adjmask<<<2048, 256, 0, stream>>>(adj2, mask2);
    k_embed<<<2048, 256, 0, stream>>>(x, Ew, h);

    for (int k = 0; k < 4; k++) {
        int nhop = k + 1;
        for (int br = 0; br < 2; br++) {
            const unsigned int* msk = br ? mask2 : mask1;
            float* zf = br ? z2 : z1;
            const float* pa = (k == 0) ? h : z2;
            const float* pb = (k == 0) ? nullptr : z1;
            k_proj<<<512, 256, 0, stream>>>(pa, pb, Wf16 + (size_t)k * 16384, gb + k * 128,
                                            AT16 + (size_t)k * 16384, hbr, hbr16, hA16, zT0, rsb);
            k_E<<<dim3(16, 16, NB), 256, 0, stream>>>(hA16, hbr16, msk, E2, rsb);
            k_rsinv<<<64, 256, 0, stream>>>(rsb, rsr16);
            k_az<<<dim3(32, NB), 256, 0, stream>>>(E2, rsr16, zT0, hbr, cfb, az, nullptr, 0);
            if (nhop == 1) {
                k_gate<<<256, 256, 0, stream>>>(hbr, az, gatew + k * 256, gateb + k,
                                                cfb, zf, nullptr, 1);
            } else {
                k_gate<<<256, 256, 0, stream>>>(hbr, az, gatew + k * 256, gateb + k,
                                                cfb, nullptr, zT1, 0);
                half_t* zi = zT1; half_t* zo = zT0;
                for (int hop = 2; hop < nhop; hop++) {
                    k_az<<<dim3(32, NB), 256, 0, stream>>>(E2, rsr16, zi, hbr, cfb,
                                                           nullptr, zo, 1);
                    half_t* tswap = zi; zi = zo; zo = tswap;
                }
                k_az<<<dim3(32, NB), 256, 0, stream>>>(E2, rsr16, zi, hbr, cfb, zf, nullptr, 2);
            }
        }
    }
    k_pool<<<dim3(8, NB), 256, 0, stream>>>(z2, z1, valid, partb);
    k_mlp<<<16, 128, 0, stream>>>(partb, valid, w0, b0, w1, b1, w2, b2, w3, b3, out);
}

// Round 4
// 922.127 us; speedup vs baseline: 1.6509x; 1.6509x over previous
//
#include <hip/hip_runtime.h>

typedef _Float16 half_t;
typedef _Float16 half8 __attribute__((ext_vector_type(8)));
typedef _Float16 half4v __attribute__((ext_vector_type(4)));
typedef float floatx4 __attribute__((ext_vector_type(4)));

#define MFMA(a,b,c) __builtin_amdgcn_mfma_f32_16x16x32_f16(a,b,c,0,0,0)

#define NB 16
#define NLEN 1024
#define DD 128
#define BN (NB*NLEN)
#define BND ((size_t)NB*NLEN*DD)
#define BNN ((size_t)NB*NLEN*NLEN)

// ---------------------------------------------------------------- embed: h = x @ Ew^T (fp32, once)
__global__ __launch_bounds__(256)
void k_embed(const float* __restrict__ x, const float* __restrict__ Ew, float* __restrict__ h) {
    __shared__ float rows[8][DD];
    int g = blockIdx.x * 8;
    int tid = threadIdx.x;
    {
        int nl = tid >> 5, c4 = (tid & 31) * 4;
        *(float4*)&rows[nl][c4] = *(const float4*)&x[(size_t)(g + nl) * DD + c4];
    }
    __syncthreads();
    int t = tid & 127, half = tid >> 7;
    const float* wr = Ew + (size_t)t * DD;
    float acc[4] = {0.f, 0.f, 0.f, 0.f};
    for (int k = 0; k < DD; k++) {
        float w = wr[k];
#pragma unroll
        for (int m = 0; m < 4; m++) acc[m] += rows[half + 2 * m][k] * w;
    }
#pragma unroll
    for (int m = 0; m < 4; m++) h[(size_t)(g + half + 2 * m) * DD + t] = acc[m];
}

// ---------------- adjacency -> bitmask
__global__ __launch_bounds__(256)
void k_adjmask(const float* __restrict__ adj, unsigned int* __restrict__ mask) {
    int widx = blockIdx.x * 256 + threadIdx.x;
    const float* p = adj + (size_t)widx * 32;
    unsigned int m = 0;
#pragma unroll
    for (int i = 0; i < 32; i += 4) {
        float4 v = *(const float4*)&p[i];
        m |= (v.x > 0.f ? 1u : 0u) << i;
        m |= (v.y > 0.f ? 1u : 0u) << (i + 1);
        m |= (v.z > 0.f ? 1u : 0u) << (i + 2);
        m |= (v.w > 0.f ? 1u : 0u) << (i + 3);
    }
    mask[widx] = m;
}

// ---------------- weight casts: Wf16 = gW row-major; ST16[e][d] = gA[d][e] + gA[e][d]  (S = A+A^T)
__global__ __launch_bounds__(256)
void k_wcast(const float* __restrict__ gW, const float* __restrict__ gA,
             half_t* __restrict__ Wf, half_t* __restrict__ STf) {
    int i = blockIdx.x * 256 + threadIdx.x;
    Wf[i] = (half_t)gW[i];
    int base = i & ~16383;
    int lrem = i & 16383;
    int d = lrem >> 7, e = lrem & 127;
    STf[base + (e << 7) + d] = (half_t)(gA[i] + gA[base + (e << 7) + d]);
}

// ---------------- proj (MFMA, once per layer): in = pa - pb; hbr = in@W^T + b ; hS = hbr@S
__global__ __launch_bounds__(256)
void k_proj(const float* __restrict__ pa, const float* __restrict__ pb,
            const half_t* __restrict__ Wf, const float* __restrict__ bias,
            const half_t* __restrict__ STf,
            float* __restrict__ hbr, half_t* __restrict__ hbr16, half_t* __restrict__ hS16,
            float* __restrict__ rsbz) {
    __shared__ half_t htile[32 * 136];
    __shared__ half_t hbtile[32 * 136];
    int gblk = blockIdx.x;
    int g = gblk * 32;
    int t = threadIdx.x;
    if (gblk < 128) rsbz[gblk * 256 + t] = 0.f;   // zero rsb[2][BN]
    int w = t >> 6, l = t & 63, q = l >> 4, l15 = l & 15;
#pragma unroll
    for (int v = 0; v < 4; v++) {
        int idx = v * 256 + t; int r = idx >> 5, c4 = (idx & 31) * 4;
        size_t gi = ((size_t)(g + r) << 7) + c4;
        float4 hv = *(const float4*)&pa[gi];
        if (pb) {
            float4 bv = *(const float4*)&pb[gi];
            hv.x -= bv.x; hv.y -= bv.y; hv.z -= bv.z; hv.w -= bv.w;
        }
        half4v hh = {(half_t)hv.x, (half_t)hv.y, (half_t)hv.z, (half_t)hv.w};
        *(half4v*)&htile[r * 136 + c4] = hh;
    }
    __syncthreads();
    int rowh = (w & 1) * 16;
    int c0 = (w >> 1) * 4;
    half8 a1[4];
#pragma unroll
    for (int kc = 0; kc < 4; kc++) a1[kc] = *(const half8*)&htile[(rowh + l15) * 136 + kc * 32 + q * 8];
    floatx4 acc[4];
#pragma unroll
    for (int cc = 0; cc < 4; cc++) {
        int col = (c0 + cc) * 16 + l15;
        floatx4 a = {0.f, 0.f, 0.f, 0.f};
#pragma unroll
        for (int kc = 0; kc < 4; kc++) {
            half8 bf = *(const half8*)&Wf[((size_t)col << 7) + kc * 32 + q * 8];
            a = MFMA(a1[kc], bf, a);
        }
        float bv = bias[col];
        a.x += bv; a.y += bv; a.z += bv; a.w += bv;
        acc[cc] = a;
    }
#pragma unroll
    for (int cc = 0; cc < 4; cc++) {
        int col = (c0 + cc) * 16 + l15;
#pragma unroll
        for (int r = 0; r < 4; r++) {
            int rowl = rowh + q * 4 + r;
            float vv = acc[cc][r];
            hbr[((size_t)(g + rowl) << 7) + col] = vv;
            hbtile[rowl * 136 + col] = (half_t)vv;
        }
    }
    __syncthreads();
    half8 a2[4];
#pragma unroll
    for (int kc = 0; kc < 4; kc++) a2[kc] = *(const half8*)&hbtile[(rowh + l15) * 136 + kc * 32 + q * 8];
#pragma unroll
    for (int cc = 0; cc < 4; cc++) {
        int col = (c0 + cc) * 16 + l15;
        floatx4 a = {0.f, 0.f, 0.f, 0.f};
#pragma unroll
        for (int kc = 0; kc < 4; kc++) {
            half8 bf = *(const half8*)&STf[((size_t)col << 7) + kc * 32 + q * 8];
            a = MFMA(a2[kc], bf, a);
        }
        acc[cc] = a;
    }
    __syncthreads();
#pragma unroll
    for (int cc = 0; cc < 4; cc++) {
        int col = (c0 + cc) * 16 + l15;
#pragma unroll
        for (int r = 0; r < 4; r++) htile[(rowh + q * 4 + r) * 136 + col] = (half_t)acc[cc][r];
    }
    __syncthreads();
#pragma unroll
    for (int v = 0; v < 2; v++) {
        int idx = v * 256 + t; int r = idx >> 4, c8 = (idx & 15) * 8;
        *(half8*)&hS16[((size_t)(g + r) << 7) + c8] = *(const half8*)&htile[r * 136 + c8];
        *(half8*)&hbr16[((size_t)(g + r) << 7) + c8] = *(const half8*)&hbtile[r * 136 + c8];
    }
}

// ---------------- triangular fused E (both branches): em = hS_i . hbr_j (symmetric, K=128)
// per branch: E2 = edge?exp(em-8):0 (f16) to tile + mirror; rsb += row/col sums of (edge?exp:CN)
__global__ __launch_bounds__(256)
void k_E(const half_t* __restrict__ hS16, const half_t* __restrict__ hbr16,
         const unsigned int* __restrict__ mask1g, const unsigned int* __restrict__ mask2g,
         half_t* __restrict__ E2, float* __restrict__ rsb) {
    int b = blockIdx.y;
    int u = blockIdx.x;            // 0..135 triangular
    int ti = 0;
    while (u >= 16 - ti) { u -= 16 - ti; ti++; }
    int tj = ti + u;
    __shared__ half_t HSi[64 * 136];
    __shared__ half_t HBj[64 * 136];
    __shared__ unsigned int mk[2][128];
    __shared__ float rowp[4][64];
    __shared__ float colp[64];
    half_t* est  = HSi;            // 64*72 overlay after compute
    half_t* estT = HBj;
    int t = threadIdx.x, w = t >> 6, l = t & 63, q = l >> 4, l15 = l & 15;
    const half_t* Sb = hS16 + ((size_t)b << 17);
    const half_t* Hb = hbr16 + ((size_t)b << 17);
#pragma unroll
    for (int v = 0; v < 2; v++) {
        int idx = v * 256 + t; int r = idx >> 4, c8 = (idx & 15) * 8;
        *(half8*)&HSi[r * 136 + c8] = *(const half8*)&Sb[((size_t)(ti * 64 + r) << 7) + c8];
        *(half8*)&HBj[r * 136 + c8] = *(const half8*)&Hb[((size_t)(tj * 64 + r) << 7) + c8];
    }
    {
        int r = (t & 127) >> 1, wsel = t & 1;
        const unsigned int* mg = (t < 128) ? mask1g : mask2g;
        mk[t >> 7][t & 127] = mg[(size_t)(b * 1024 + ti * 64 + r) * 32 + tj * 2 + wsel];
    }
    __syncthreads();
    half8 Bf[4];
#pragma unroll
    for (int kc = 0; kc < 4; kc++) Bf[kc] = *(const half8*)&HBj[(w * 16 + l15) * 136 + kc * 32 + q * 8];
    floatx4 acc[4];
#pragma unroll
    for (int rt = 0; rt < 4; rt++) {
        floatx4 a = {0.f, 0.f, 0.f, 0.f};
#pragma unroll
        for (int kc = 0; kc < 4; kc++)
            a = MFMA(*(const half8*)&HSi[(rt * 16 + l15) * 136 + kc * 32 + q * 8], Bf[kc], a);
        acc[rt] = a;
    }
    float ev[4][4];
#pragma unroll
    for (int rt = 0; rt < 4; rt++)
#pragma unroll
        for (int r = 0; r < 4; r++) ev[rt][r] = __expf(acc[rt][r] - 8.f);
    __syncthreads();   // all frag reads done; est/estT overlay safe
    const float CN = 0.000335462627903f;   // exp(-8)
    int jc = w * 16 + l15;
    for (int br = 0; br < 2; br++) {
        float colsum = 0.f;
#pragma unroll
        for (int rt = 0; rt < 4; rt++) {
#pragma unroll
            for (int r = 0; r < 4; r++) {
                int row = rt * 16 + q * 4 + r;
                bool edge = (mk[br][row * 2 + (jc >> 5)] >> (jc & 31)) & 1u;
                float tv = edge ? ev[rt][r] : CN;
                half_t sv = edge ? (half_t)ev[rt][r] : (half_t)0.f;
                est[row * 72 + jc] = sv;
                estT[jc * 72 + row] = sv;
                colsum += tv;
                float s = tv;
                s += __shfl_xor(s, 1); s += __shfl_xor(s, 2);
                s += __shfl_xor(s, 4); s += __shfl_xor(s, 8);
                if (l15 == 0) rowp[w][row] = s;
            }
        }
        colsum += __shfl_xor(colsum, 16);
        colsum += __shfl_xor(colsum, 32);
        if (q == 0) colp[jc] = colsum;
        __syncthreads();
        half_t* Eb = E2 + ((size_t)(br * 16 + b) << 20);
#pragma unroll
        for (int v = 0; v < 2; v++) {
            int idx = v * 256 + t; int r = idx >> 3, c8 = (idx & 7) * 8;
            *(half8*)&Eb[((size_t)(ti * 64 + r) << 10) + tj * 64 + c8] = *(const half8*)&est[r * 72 + c8];
        }
        if (ti != tj) {
#pragma unroll
            for (int v = 0; v < 2; v++) {
                int idx = v * 256 + t; int r = idx >> 3, c8 = (idx & 7) * 8;
                *(half8*)&Eb[((size_t)(tj * 64 + r) << 10) + ti * 64 + c8] = *(const half8*)&estT[r * 72 + c8];
            }
        }
        if (t < 64) {
            float rsum = rowp[0][t] + rowp[1][t] + rowp[2][t] + rowp[3][t];
            atomicAdd(&rsb[br * BN + b * 1024 + ti * 64 + t], rsum);
            if (ti != tj) atomicAdd(&rsb[br * BN + b * 1024 + tj * 64 + t], colp[t]);
        }
        __syncthreads();
    }
}

// ---------------- rsr = 1/rsb; zT = f16(rsr[n] * hbr[n][d]) transposed, per branch
__global__ __launch_bounds__(256)
void k_rsz(const float* __restrict__ rsb, const float* __restrict__ hbr,
           float* __restrict__ rsr, half_t* __restrict__ zT) {
    int br = blockIdx.z, b = blockIdx.y, n0 = blockIdx.x * 64;
    __shared__ float rsl[64];
    __shared__ half_t tile[128 * 72];
    int t = threadIdx.x;
    if (t < 64) {
        float v = 1.f / rsb[br * BN + b * 1024 + n0 + t];
        rsr[br * BN + b * 1024 + n0 + t] = v;
        rsl[t] = v;
    }
    __syncthreads();
#pragma unroll
    for (int v = 0; v < 8; v++) {
        int idx = v * 256 + t; int r = idx >> 5, c4 = (idx & 31) * 4;
        float4 hv = *(const float4*)&hbr[((size_t)(b * 1024 + n0 + r) << 7) + c4];
        float rs = rsl[r];
        tile[(c4 + 0) * 72 + r] = (half_t)(rs * hv.x);
        tile[(c4 + 1) * 72 + r] = (half_t)(rs * hv.y);
        tile[(c4 + 2) * 72 + r] = (half_t)(rs * hv.z);
        tile[(c4 + 3) * 72 + r] = (half_t)(rs * hv.w);
    }
    __syncthreads();
#pragma unroll
    for (int v = 0; v < 4; v++) {
        int idx = v * 256 + t; int d = idx >> 3, c8 = (idx & 7) * 8;
        *(half8*)&zT[(((size_t)((br * 16 + b) * 128 + d)) << 10) + n0 + c8] = *(const half8*)&tile[d * 72 + c8];
    }
}

// ---------------- az = E2 @ (rs.z) ; both branches. mode0: az16=relu. mode1: blend->zTout(scaled).
// mode2: blend->zf f32.
__global__ __launch_bounds__(256)
void k_az(const half_t* __restrict__ E2, const half_t* __restrict__ zTin,
          const float* __restrict__ rsr, const float* __restrict__ hbr,
          const float* __restrict__ cfb, half_t* __restrict__ az16,
          float* __restrict__ zfo, half_t* __restrict__ zTout, int mode) {
    __shared__ half_t Pt[32 * 72];
    __shared__ half_t Zt[128 * 72];
    int br = blockIdx.z, b = blockIdx.y, i0 = blockIdx.x * 32;
    int t = threadIdx.x, w = t >> 6, l = t & 63, q = l >> 4, l15 = l & 15;
    int rowg = (w & 1) * 16, colh = (w >> 1) * 64;
    const half_t* Eb = E2 + ((size_t)(br * 16 + b) << 20);
    const half_t* Zb = zTin + ((size_t)(br * 16 + b) << 17);
    floatx4 acc[4] = {};
    for (int k0 = 0; k0 < 1024; k0 += 64) {
        {
            int r = t >> 3, c8 = (t & 7) * 8;
            *(half8*)&Pt[r * 72 + c8] = *(const half8*)&Eb[((size_t)(i0 + r) << 10) + k0 + c8];
        }
#pragma unroll
        for (int v = 0; v < 4; v++) {
            int idx = v * 256 + t; int r = idx >> 3, c8 = (idx & 7) * 8;
            *(half8*)&Zt[r * 72 + c8] = *(const half8*)&Zb[((size_t)r << 10) + k0 + c8];
        }
        __syncthreads();
        half8 af0 = *(const half8*)&Pt[(rowg + l15) * 72 + q * 8];
        half8 af1 = *(const half8*)&Pt[(rowg + l15) * 72 + 32 + q * 8];
#pragma unroll
        for (int cc = 0; cc < 4; cc++) {
            acc[cc] = MFMA(af0, *(const half8*)&Zt[(colh + cc * 16 + l15) * 72 + q * 8], acc[cc]);
            acc[cc] = MFMA(af1, *(const half8*)&Zt[(colh + cc * 16 + l15) * 72 + 32 + q * 8], acc[cc]);
        }
        __syncthreads();
    }
    int nloc = i0 + rowg + q * 4;
    if (mode == 0) {
        half_t* azs = Zt;   // 32x136 staging
#pragma unroll
        for (int cc = 0; cc < 4; cc++) {
            int col = colh + cc * 16 + l15;
#pragma unroll
            for (int r = 0; r < 4; r++)
                azs[(rowg + q * 4 + r) * 136 + col] = (half_t)fmaxf(acc[cc][r], 0.f);
        }
        __syncthreads();
#pragma unroll
        for (int v = 0; v < 2; v++) {
            int idx = v * 256 + t; int r = idx >> 3, c8 = (idx & 7) * 8;
            *(half8*)&az16[(size_t)br * BND + ((size_t)(b * 1024 + i0 + r) << 7) + c8]
                = *(const half8*)&azs[r * 136 + c8];
        }
    } else {
        float4 cf4 = *(const float4*)&cfb[br * BN + b * 1024 + nloc];
        float4 rs4 = *(const float4*)&rsr[br * BN + b * 1024 + nloc];
        const float* cfp = &cf4.x; const float* rsp = &rs4.x;
#pragma unroll
        for (int cc = 0; cc < 4; cc++) {
            int col = colh + cc * 16 + l15;
            half4v zt;
#pragma unroll
            for (int r = 0; r < 4; r++) {
                float azv = fmaxf(acc[cc][r], 0.f);
                float hv = hbr[((size_t)(b * 1024 + nloc + r) << 7) + col];
                float zv = cfp[r] * hv + (1.f - cfp[r]) * azv;
                if (mode == 2) zfo[(size_t)br * BND + ((size_t)(b * 1024 + nloc + r) << 7) + col] = zv;
                zt[r] = (half_t)(rsp[r] * zv);
            }
            if (mode == 1)
                *(half4v*)&zTout[(((size_t)((br * 16 + b) * 128 + col)) << 10) + nloc] = zt;
        }
    }
}

// ---------------- gate: cf = sigmoid([hbr,az].gw+gb); z = cf*hbr+(1-cf)*az
// gmode0 -> zT (rs-scaled f16 transposed); gmode1 -> zf f32
__global__ __launch_bounds__(256)
void k_gate(const float* __restrict__ hbr, const half_t* __restrict__ az16,
            const float* __restrict__ gw, const float* __restrict__ gb_,
            const float* __restrict__ rsr, float* __restrict__ cfb,
            float* __restrict__ zf, half_t* __restrict__ zT, int gmode) {
    int br = blockIdx.y;
    int n0g = blockIdx.x * 64;
    int b = n0g >> 10, nl0 = n0g & 1023;
    int t = threadIdx.x;
    __shared__ float cfs[64];
    __shared__ float rsl[64];
    __shared__ half_t tile[128 * 72];
    if (gmode == 0 && t < 64) rsl[t] = rsr[br * BN + n0g + t];
    int node = t >> 2, seg = t & 3;
    float acc = 0.f;
    if (seg < 2) {
        const float* row = hbr + ((size_t)(n0g + node) << 7) + seg * 64;
        const float* gwp = gw + seg * 64;
#pragma unroll
        for (int i = 0; i < 64; i += 4) {
            float4 v = *(const float4*)&row[i];
            float4 g2 = *(const float4*)&gwp[i];
            acc += v.x * g2.x + v.y * g2.y + v.z * g2.z + v.w * g2.w;
        }
    } else {
        const half_t* row = az16 + (size_t)br * BND + ((size_t)(n0g + node) << 7) + (seg - 2) * 64;
        const float* gwp = gw + 128 + (seg - 2) * 64;
#pragma unroll
        for (int i = 0; i < 64; i += 8) {
            half8 v = *(const half8*)&row[i];
#pragma unroll
            for (int j = 0; j < 8; j++) acc += (float)v[j] * gwp[i + j];
        }
    }
    acc += __shfl_xor(acc, 1);
    acc += __shfl_xor(acc, 2);
    if (seg == 0) {
        float cf = 1.f / (1.f + __expf(-(acc + gb_[0])));
        cfs[node] = cf;
        cfb[br * BN + n0g + node] = cf;
    }
    __syncthreads();
#pragma unroll
    for (int v = 0; v < 8; v++) {
        int idx = v * 256 + t; int r = idx >> 5, c4 = (idx & 31) * 4;
        size_t gi = ((size_t)(n0g + r) << 7) + c4;
        float4 hv = *(const float4*)&hbr[gi];
        half4v av = *(const half4v*)&az16[(size_t)br * BND + gi];
        float cf = cfs[r];
        float4 zv;
        zv.x = cf * hv.x + (1.f - cf) * (float)av[0];
        zv.y = cf * hv.y + (1.f - cf) * (float)av[1];
        zv.z = cf * hv.z + (1.f - cf) * (float)av[2];
        zv.w = cf * hv.w + (1.f - cf) * (float)av[3];
        if (gmode == 1) *(float4*)&zf[(size_t)br * BND + gi] = zv;
        else {
            float rs = rsl[r];
            tile[(c4 + 0) * 72 + r] = (half_t)(rs * zv.x);
            tile[(c4 + 1) * 72 + r] = (half_t)(rs * zv.y);
            tile[(c4 + 2) * 72 + r] = (half_t)(rs * zv.z);
            tile[(c4 + 3) * 72 + r] = (half_t)(rs * zv.w);
        }
    }
    if (gmode == 0) {
        __syncthreads();
#pragma unroll
        for (int v = 0; v < 4; v++) {
            int idx = v * 256 + t; int d = idx >> 3, c8 = (idx & 7) * 8;
            *(half8*)&zT[(((size_t)((br * 16 + b) * 128 + d)) << 10) + nl0 + c8]
                = *(const half8*)&tile[d * 72 + c8];
        }
    }
}

// ---------------- partial masked pool of (zf1 - zf0)
__global__ __launch_bounds__(256)
void k_pool(const float* __restrict__ z2, const float* __restrict__ z1,
            const float* __restrict__ valid, float* __restrict__ part) {
    int b = blockIdx.y, s = blockIdx.x;
    int t = threadIdx.x, d = t & 127, hf = t >> 7;
    __shared__ float red[128];
    float acc = 0.f;
    int nbase = s * 128 + hf * 64;
    for (int n = nbase; n < nbase + 64; n++) {
        size_t gi = ((size_t)(b * 1024 + n) << 7) + d;
        acc += (z2[gi] - z1[gi]) * valid[b * 1024 + n];
    }
    if (hf) red[d] = acc;
    __syncthreads();
    if (!hf) part[(b * 8 + s) * 128 + d] = acc + red[d];
}

// ---------------- final reduce + MLP head
__global__ __launch_bounds__(128)
void k_mlp(const float* __restrict__ part, const float* __restrict__ valid,
           const float* __restrict__ w0, const float* __restrict__ b0,
           const float* __restrict__ w1, const float* __restrict__ b1,
           const float* __restrict__ w2, const float* __restrict__ b2,
           const float* __restrict__ w3, const float* __restrict__ b3,
           float* __restrict__ out) {
    int b = blockIdx.x, t = threadIdx.x;
    __shared__ float y0[DD], y1[DD];
    __shared__ float sred[2];
    float vs = 0.f;
    for (int n = t; n < NLEN; n += 128) vs += valid[b * NLEN + n];
    for (int off = 32; off; off >>= 1) vs += __shfl_down(vs, off);
    if ((t & 63) == 0) sred[t >> 6] = vs;
    __syncthreads();
    float vsum = sred[0] + sred[1];
    float acc = 0.f;
#pragma unroll
    for (int s = 0; s < 8; s++) acc += part[(b * 8 + s) * 128 + t];
    y0[t] = acc / vsum;
    __syncthreads();
    float a = b0[t];
    for (int k = 0; k < DD; k++) a += y0[k] * w0[t * DD + k];
    y1[t] = fmaxf(a, 0.f);
    __syncthreads();
    a = b1[t];
    for (int k = 0; k < DD; k++) a += y1[k] * w1[t * DD + k];
    y0[t] = fmaxf(a, 0.f);
    __syncthreads();
    a = b2[t];
    for (int k = 0; k < DD; k++) a += y0[k] * w2[t * DD + k];
    y1[t] = fmaxf(a, 0.f);
    __syncthreads();
    float p = y1[t] * w3[t];
    for (int off = 32; off; off >>= 1) p += __shfl_down(p, off);
    if ((t & 63) == 0) sred[t >> 6] = p;
    __syncthreads();
    if (t == 0) out[b] = 1.f / (1.f + __expf(-(sred[0] + sred[1] + b3[0])));
}

extern "C" void kernel_launch(void* const* d_in, const int* in_sizes, int n_in,
                              void* d_out, int out_size, void* d_ws, size_t ws_size,
                              hipStream_t stream) {
    (void)in_sizes; (void)n_in; (void)out_size; (void)ws_size;
    const float* x     = (const float*)d_in[0];
    const float* adj1  = (const float*)d_in[1];
    const float* adj2  = (const float*)d_in[2];
    const float* valid = (const float*)d_in[3];
    const float* Ew    = (const float*)d_in[4];
    const float* gW    = (const float*)d_in[5];
    const float* gb    = (const float*)d_in[6];
    const float* gA    = (const float*)d_in[7];
    const float* gatew = (const float*)d_in[8];
    const float* gateb = (const float*)d_in[9];
    const float* w0 = (const float*)d_in[10]; const float* b0 = (const float*)d_in[11];
    const float* w1 = (const float*)d_in[12]; const float* b1 = (const float*)d_in[13];
    const float* w2 = (const float*)d_in[14]; const float* b2 = (const float*)d_in[15];
    const float* w3 = (const float*)d_in[16]; const float* b3 = (const float*)d_in[17];
    float* out = (float*)d_out;

    char* p = (char*)d_ws;
    float* h    = (float*)p; p += BND * 4;
    float* hbr  = (float*)p; p += BND * 4;
    float* zf   = (float*)p; p += 2 * BND * 4;          // [br]
    float* rsb  = (float*)p; p += 2 * BN * 4;
    float* rsr  = (float*)p; p += 2 * BN * 4;
    float* cfb  = (float*)p; p += 2 * BN * 4;
    float* partb = (float*)p; p += (size_t)NB * 8 * 128 * 4;
    half_t* hbr16 = (half_t*)p; p += BND * 2;
    half_t* hS16  = (half_t*)p; p += BND * 2;
    half_t* az16  = (half_t*)p; p += 2 * BND * 2;
    half_t* zTa   = (half_t*)p; p += 2 * BND * 2;
    half_t* zTb   = (half_t*)p; p += 2 * BND * 2;
    half_t* E2    = (half_t*)p; p += 2 * BNN * 2;
    unsigned int* mask1 = (unsigned int*)p; p += (BNN / 32) * 4;
    unsigned int* mask2 = (unsigned int*)p; p += (BNN / 32) * 4;
    half_t* Wf16 = (half_t*)p; p += (size_t)4 * 128 * 128 * 2;
    half_t* ST16 = (half_t*)p; p += (size_t)4 * 128 * 128 * 2;

    k_wcast<<<256, 256, 0, stream>>>(gW, gA, Wf16, ST16);
    k_adjmask<<<2048, 256, 0, stream>>>(adj1, mask1);
    k_adjmask<<<2048, 256, 0, stream>>>(adj2, mask2);
    k_embed<<<2048, 256, 0, stream>>>(x, Ew, h);

    for (int k = 0; k < 4; k++) {
        int nhop = k + 1;
        const float* pa = k ? (zf + BND) : h;
        const float* pb = k ? zf : nullptr;
        k_proj<<<512, 256, 0, stream>>>(pa, pb, Wf16 + (size_t)k * 16384, gb + k * 128,
                                        ST16 + (size_t)k * 16384, hbr, hbr16, hS16, rsb);
        k_E<<<dim3(136, NB), 256, 0, stream>>>(hS16, hbr16, mask1, mask2, E2, rsb);
        k_rsz<<<dim3(16, NB, 2), 256, 0, stream>>>(rsb, hbr, rsr, zTa);
        k_az<<<dim3(32, NB, 2), 256, 0, stream>>>(E2, zTa, rsr, hbr, cfb, az16,
                                                  nullptr, nullptr, 0);
        if (nhop == 1) {
            k_gate<<<dim3(256, 2), 256, 0, stream>>>(hbr, az16, gatew + k * 256, gateb + k,
                                                     rsr, cfb, zf, nullptr, 1);
        } else {
            k_gate<<<dim3(256, 2), 256, 0, stream>>>(hbr, az16, gatew + k * 256, gateb + k,
                                                     rsr, cfb, nullptr, zTb, 0);
            half_t* zi = zTb; half_t* zo = zTa;
            for (int hop = 2; hop < nhop; hop++) {
                k_az<<<dim3(32, NB, 2), 256, 0, stream>>>(E2, zi, rsr, hbr, cfb,
                                                          nullptr, nullptr, zo, 1);
                half_t* tsw = zi; zi = zo; zo = tsw;
            }
            k_az<<<dim3(32, NB, 2), 256, 0, stream>>>(E2, zi, rsr, hbr, cfb,
                                                      nullptr, zf, nullptr, 2);
        }
    }
    k_pool<<<dim3(8, NB), 256, 0, stream>>>(zf + BND, zf, valid, partb);
    k_mlp<<<16, 128, 0, stream>>>(partb, valid, w0, b0, w1, b1, w2, b2, w3, b3, out);
}